// Round 10
// baseline (786.923 us; speedup 1.0000x reference)
//
#include <hip/hip_runtime.h>
#include <cstddef>

// Problem dims
#define CI_  64
#define CO_  256
#define DD_  31
#define HH_  96
#define WW_  96
#define HW_  (HH_*WW_)      // 9216
#define DHW_ (DD_*HW_)      // 285696
#define EPSV 1e-5f

// Padded channels-last fp16 input: xt[cig8][pd33][ph98][pw98][ci8]
#define PD_   33
#define PH_   98
#define PW_   98
#define PHW_  9604          // 98*98
#define PDHW_ 316932        // 33*9604

// Conv tile: M=128 (8h x 16w) x N=256, one d. 8 waves: 2 (M) x 4 (N).
// LDS halo: [dd3][row10][cig8][col18][ci8] halves — linear in task order.
#define S_COL 8
#define S_CIG 144           // 18*8
#define S_ROW 1152          // 8*144
#define S_DD  11520         // 10*1152
#define NTASK 4320          // 3*10*8*18 real 16B tasks
#define NTASKP 4352         // padded
#define XH_N  (NTASKP*8)    // 34816 halves = 69632 B

#define NTILE 72            // 12 hti * 6 wti per d-plane
#define NPAIR 1116          // 2232 tiles / 2 per block

// gates layout: per (d,bx) block of 32768 halves: [c 64][sp 128][gate 4]
#define GBLK 32768
#define GDSTR ((size_t)NTILE * GBLK)

// prep kernel block ranges
#define PREP_RB 216         // repack: 55296 threads
#define PREP_PB 1239        // pad_zero: 316932 threads
#define PREP_TB 279         // transpose: 71424 threads
#define PREP_NB (PREP_RB + PREP_PB + PREP_TB)

typedef _Float16 half8   __attribute__((ext_vector_type(8)));
typedef _Float16 half4v  __attribute__((ext_vector_type(4)));
typedef float    float4v __attribute__((ext_vector_type(4)));
typedef float    float16v __attribute__((ext_vector_type(16)));

__device__ __forceinline__ void gl_lds16(const _Float16* g, _Float16* l) {
  __builtin_amdgcn_global_load_lds(
      (const __attribute__((address_space(1))) unsigned int*)(g),
      (__attribute__((address_space(3))) unsigned int*)(l), 16, 0, 0);
}

// -------- fused prep: weight repack + border zero + interior transpose --------
// repack: w[co][ci][27] fp32 -> wr3[t 27][kq 4][cob 8][lane 64][e 8] fp16
// (B fragment for mfma_32x32x16: lane l -> col = l&31 (co), k = (l>>5)*8 + e)
__global__ __launch_bounds__(256) void prep_k(const float* __restrict__ w,
                                              const float* __restrict__ x,
                                              _Float16* __restrict__ wr3,
                                              _Float16* __restrict__ xt) {
  const int bid = blockIdx.x;
  if (bid < PREP_RB) {
    int idx = bid * 256 + threadIdx.x;          // 27*4*8*64 = 55296
    int lane = idx & 63;
    int cob  = (idx >> 6) & 7;
    int kq   = (idx >> 9) & 3;
    int t    = idx >> 11;
    int co   = cob * 32 + (lane & 31);
    int cib  = kq * 16 + (lane >> 5) * 8;
    half8 v;
#pragma unroll
    for (int s = 0; s < 8; s++)
      v[s] = (_Float16)w[(size_t)co * 1728 + (size_t)(cib + s) * 27 + t];
    *(half8*)(wr3 + (size_t)idx * 8) = v;
  } else if (bid < PREP_RB + PREP_PB) {
    int p = (bid - PREP_RB) * 256 + threadIdx.x;
    if (p >= PDHW_) return;
    int pd  = p / PHW_;
    int rem = p - pd * PHW_;
    int ph  = rem / PW_;
    int pw  = rem - ph * PW_;
    bool in = (pd >= 1) & (pd <= DD_) & (ph >= 1) & (ph <= HH_) & (pw >= 1) & (pw <= WW_);
    if (in) return;
    half8 z = (half8)(_Float16)0.f;
#pragma unroll
    for (int cig = 0; cig < 8; cig++)
      *(half8*)(xt + ((size_t)cig * PDHW_ + p) * 8) = z;
  } else {
    int idx = (bid - PREP_RB - PREP_PB) * 256 + threadIdx.x;  // 31*96*24 = 71424
    if (idx >= 31 * 96 * 24) return;
    int wq  = idx % 24;
    int rem = idx / 24;
    int h   = rem % 96;
    int d   = rem / 96;
    const float* xp = x + (size_t)d * HW_ + (size_t)h * WW_ + wq * 4;
    size_t p0 = (size_t)(d + 1) * PHW_ + (size_t)(h + 1) * PW_ + (wq * 4 + 1);
#pragma unroll 1
    for (int cig = 0; cig < 8; cig++) {
      float4 vv[8];
#pragma unroll
      for (int s = 0; s < 8; s++)
        vv[s] = *(const float4*)(xp + (size_t)(cig * 8 + s) * DHW_);
#pragma unroll
      for (int k = 0; k < 4; k++) {
        half8 o;
#pragma unroll
        for (int s = 0; s < 8; s++) o[s] = (_Float16)(&vv[s].x)[k];
        *(half8*)(xt + ((size_t)cig * PDHW_ + p0 + k) * 8) = o;
      }
    }
  }
}

__device__ __forceinline__ float tanh_f(float v) {
  float t = __expf(-2.f * fabsf(v));
  return copysignf((1.f - t) * __builtin_amdgcn_rcpf(1.f + t), v);
}
__device__ __forceinline__ float sigm_f(float v) {
  return __builtin_amdgcn_rcpf(1.f + __expf(-v));
}

// -------- conv3d (implicit GEMM, 32x32x16 f16 MFMA) + BN + act -> gates ----
// PERSISTENT 2-TILE blocks, double-buffered LDS halo: stage A; [issue stage B];
// kloop A; barrier (B landed under kloop A); epi A; kloop B; epi B.
// 1 block/CU (139KB LDS), 8 waves (2 M x 4 N), 256-reg budget (no spill).
__global__ __launch_bounds__(512, 2) void conv_mfma_k(
    const _Float16* __restrict__ xt, const _Float16* __restrict__ wr3,
    const float* __restrict__ gamma, const float* __restrict__ beta,
    const float* __restrict__ mean, const float* __restrict__ var,
    _Float16* __restrict__ gates)
{
  __shared__ _Float16 xh0[XH_N];
  __shared__ _Float16 xh1[XH_N];

  // bijective chunked XCD swizzle of 1116 pairs (q=139, r=4)
  const int orig = blockIdx.x;
  const int xcd  = orig & 7;
  const int base = orig >> 3;
  const int wg   = (xcd < 4 ? xcd * 140 : 560 + (xcd - 4) * 139) + base;
  const int flat0 = wg * 2;                  // NTILE even -> pair shares d
  const int d    = flat0 / NTILE;
  const int bxA  = flat0 - d * NTILE;
  const int bxB  = bxA + 1;

  const int tid  = threadIdx.x;
  const int lane = tid & 63;
  const int wave = __builtin_amdgcn_readfirstlane(tid >> 6);
  const int wm   = wave >> 2;        // M half (0,1)
  const int wn   = wave & 3;         // co group (64 each)
  const bool istanh = (wn == 0) || (wn == 3);

  // A lane addr: row = lane&31 -> h_off=(lane>>4)&1, w=lane&15; k-octet=lane>>5
  const int abase0 = (wm * 4 + ((lane >> 4) & 1)) * S_ROW +
                     (lane >> 5) * S_CIG + (lane & 15) * S_COL;

#define STAGE(BUF, BX)                                                        \
  {                                                                           \
    const int h0_ = ((BX) / 6) * 8, w0_ = ((BX) % 6) * 16;                    \
    _Pragma("unroll")                                                         \
    for (int it = 0; it < 9; ++it) {                                          \
      const int wb = it * 512 + wave * 64;                                    \
      if (wb < NTASKP) {                                                      \
        const int task = wb + lane;                                           \
        const int tt   = task < NTASK ? task : (NTASK - 1);                   \
        int col = tt % 18;                                                    \
        int rc  = tt / 18;                                                    \
        int cig = rc & 7;                                                     \
        int dr  = rc >> 3;                                                    \
        int dd  = dr / 10;                                                    \
        int row = dr - dd * 10;                                               \
        const _Float16* g = xt + (((size_t)cig * PDHW_ +                      \
            (size_t)(d + dd) * PHW_ + (size_t)(h0_ + row) * PW_ +             \
            (w0_ + col)) << 3);                                               \
        gl_lds16(g, (BUF) + (size_t)wb * 8);                                  \
      }                                                                       \
    }                                                                         \
  }

#define KLOOP(BUF)                                                            \
  _Pragma("unroll")                                                           \
  for (int kd = 0; kd < 3; ++kd) {                                            \
    _Pragma("unroll")                                                         \
    for (int kh = 0; kh < 3; ++kh) {                                          \
      _Pragma("unroll")                                                       \
      for (int kw = 0; kw < 3; ++kw) {                                        \
        const int t  = (kd * 3 + kh) * 3 + kw;                                \
        const int ab = abase0 + kd * S_DD + kh * S_ROW + kw * S_COL;          \
        _Pragma("unroll")                                                     \
        for (int kq = 0; kq < 4; ++kq) {                                      \
          half8 a0 = *(const half8*)((BUF) + ab + kq * 2 * S_CIG);            \
          half8 a1 = *(const half8*)((BUF) + ab + kq * 2 * S_CIG + 2 * S_ROW);\
          const _Float16* bp = wr3 +                                          \
              (((size_t)((t * 4 + kq) * 8 + wn * 2)) << 9) + (lane << 3);     \
          half8 b0 = *(const half8*)(bp);                                     \
          half8 b1 = *(const half8*)(bp + 512);                               \
          acc00 = __builtin_amdgcn_mfma_f32_32x32x16_f16(a0, b0, acc00, 0,0,0);\
          acc01 = __builtin_amdgcn_mfma_f32_32x32x16_f16(a0, b1, acc01, 0,0,0);\
          acc10 = __builtin_amdgcn_mfma_f32_32x32x16_f16(a1, b0, acc10, 0,0,0);\
          acc11 = __builtin_amdgcn_mfma_f32_32x32x16_f16(a1, b1, acc11, 0,0,0);\
        }                                                                     \
      }                                                                       \
    }                                                                         \
  }

  // C/D (32x32): col = lane&31 (co), row r = (reg&3) + 8*(reg>>2) + 4*(lane>>5)
  // spatial: h_local = wm*4 + mb*2 + (r>>4), w_local = r&15
#define EPI(BUF, BX)                                                          \
  {                                                                           \
    __syncthreads(); /* all reads of BUF done; stage-B vmcnt drained */       \
    _Pragma("unroll")                                                         \
    for (int nb = 0; nb < 2; ++nb) {                                          \
      const int cl = nb * 32 + (lane & 31);                                   \
      const int co = wn * 64 + cl;                                            \
      const float s_  = gamma[co] * rsqrtf(var[co] + EPSV);                   \
      const float bb_ = fmaf(-mean[co], s_, beta[co]);                        \
      const int cbase = cl << 10;                                             \
      const int key   = (cl & 7) << 4;                                        \
      _Pragma("unroll")                                                       \
      for (int mb = 0; mb < 2; ++mb) {                                        \
        _Pragma("unroll")                                                     \
        for (int reg = 0; reg < 16; ++reg) {                                  \
          const float va = (mb == 0) ? (nb == 0 ? acc00[reg] : acc01[reg])    \
                                     : (nb == 0 ? acc10[reg] : acc11[reg]);   \
          const int r  = (reg & 3) + 8 * (reg >> 2) + 4 * (lane >> 5);        \
          const int sp = (wm * 4 + mb * 2 + (r >> 4)) * 16 + (r & 15);        \
          float v = fmaf(va, s_, bb_);                                        \
          _Float16 a = (_Float16)(istanh ? tanh_f(v) : sigm_f(v));            \
          *(_Float16*)((char*)(BUF) + cbase +                                 \
                       (((sp << 3) + (wn << 1)) ^ key)) = a;                  \
        }                                                                     \
      }                                                                       \
    }                                                                         \
    __syncthreads();                                                          \
    _Float16* gb = gates + (size_t)(d * NTILE + (BX)) * GBLK;                 \
    _Pragma("unroll")                                                         \
    for (int rr = 0; rr < 8; rr++) {                                          \
      const int c = wave * 8 + rr;                                            \
      const half8 rv = *(const half8*)((const char*)(BUF) + (c << 10) +       \
                                       ((lane ^ (c & 7)) << 4));              \
      *(half8*)(gb + (size_t)c * 512 + lane * 8) = rv;                        \
    }                                                                         \
  }

  float16v acc00, acc01, acc10, acc11;

  // ---- tile A stage (exposed once per block) ----
  STAGE(xh0, bxA)
  __syncthreads();
  // ---- issue tile B stage; lands under kloop A ----
  STAGE(xh1, bxB)

  acc00 = (float16v)0.f; acc01 = (float16v)0.f;
  acc10 = (float16v)0.f; acc11 = (float16v)0.f;
  KLOOP(xh0)
  EPI(xh0, bxA)

  acc00 = (float16v)0.f; acc01 = (float16v)0.f;
  acc10 = (float16v)0.f; acc11 = (float16v)0.f;
  KLOOP(xh1)
  EPI(xh1, bxB)

#undef STAGE
#undef KLOOP
#undef EPI
}

// -------- SRU recurrence over d; ONE thread per (c, bx, sp); 4-deep ring ----
__global__ __launch_bounds__(256) void recurrence_k(const _Float16* __restrict__ gates,
                                                    float* __restrict__ out) {
  const int idx = blockIdx.x * 256 + threadIdx.x;   // 64*72*128 = 589824
  const int sp  = idx & 127;
  const int t2  = idx >> 7;          // c*72 + bx
  const int c   = t2 / NTILE;
  const int bx  = t2 - c * NTILE;
  const int hti = bx / 6, wti = bx - hti * 6;
  const int h   = hti * 8 + (sp >> 4);
  const int w   = wti * 16 + (sp & 15);

  const _Float16* g0 = gates + (size_t)bx * GBLK + (size_t)c * 512 + sp * 4;
  float* op = out + (size_t)c * DHW_ + (size_t)h * WW_ + w;

#define LD(dv) (*(const half4v*)(g0 + (size_t)(dv) * GDSTR))
  half4v p[4];
#pragma unroll
  for (int i = 0; i < 4; i++) p[i] = LD(i);

  float C = 0.f;
#pragma unroll
  for (int d = 0; d < DD_; d++) {       // fully unrolled: p[d&3] is static
    half4v cur = p[d & 3];
    if (d + 4 < DD_) p[d & 3] = LD(d + 4);
    float wx = (float)cur[0], f = (float)cur[1];
    float r  = (float)cur[2], x = (float)cur[3];
    C = (d == 0) ? (1.f - f) : fmaf(f, C - wx, wx);
    op[(size_t)d * HW_] = fmaf(r, C - x, x);
  }
#undef LD
}

extern "C" void kernel_launch(void* const* d_in, const int* in_sizes, int n_in,
                              void* d_out, int out_size, void* d_ws, size_t ws_size,
                              hipStream_t stream) {
  const float* x     = (const float*)d_in[0];
  const float* w     = (const float*)d_in[1];
  const float* gamma = (const float*)d_in[2];
  const float* beta  = (const float*)d_in[3];
  const float* mean  = (const float*)d_in[4];
  const float* var   = (const float*)d_in[5];
  float* out = (float*)d_out;

  // ws: [wr3: 884736 B][xt: 8*316932*16 = 40567296 B][gates: 2232*65536 B]
  _Float16* wr3   = (_Float16*)d_ws;
  _Float16* xt    = (_Float16*)((char*)d_ws + 884736);
  _Float16* gates = (_Float16*)((char*)d_ws + 884736 + 40567296);

  prep_k<<<PREP_NB, 256, 0, stream>>>(w, x, wr3, xt);
  conv_mfma_k<<<NPAIR, 512, 0, stream>>>(xt, wr3, gamma, beta, mean, var, gates);
  recurrence_k<<<(64 * NTILE * 128) / 256, 256, 0, stream>>>(gates, out);
}

// Round 11
// 399.519 us; speedup vs baseline: 1.9697x; 1.9697x over previous
//
#include <hip/hip_runtime.h>
#include <cstddef>

// Problem dims
#define CI_  64
#define CO_  256
#define DD_  31
#define HH_  96
#define WW_  96
#define HW_  (HH_*WW_)      // 9216
#define DHW_ (DD_*HW_)      // 285696
#define EPSV 1e-5f

// Padded channels-last fp16 input: xt[cig8][pd33][ph98][pw98][ci8]
#define PD_   33
#define PH_   98
#define PW_   98
#define PHW_  9604          // 98*98
#define PDHW_ 316932        // 33*9604

// Conv tile: M=128 (8h x 16w) x N=256, one d per block. 8 waves: 2 (M) x 4 (N).
// LDS halo: [dd3][row10][cig8][col18][ci8] halves — linear in task order.
#define S_COL 8
#define S_CIG 144           // 18*8
#define S_ROW 1152          // 8*144
#define S_DD  11520         // 10*1152
#define NTASK 4320          // 3*10*8*18 real 16B tasks
#define NTASKP 4352         // padded
#define XH_N  (NTASKP*8)    // 34816 halves = 69632 B

#define NTILE 72            // 12 hti * 6 wti per d-plane
#define NBLK  (NTILE*DD_)   // 2232 conv blocks (= 8*279, XCD-exact)

// gates layout: per (d,bx) block of 32768 halves: [c 64][sp 128][gate 4]
#define GBLK 32768
#define GDSTR ((size_t)NTILE * GBLK)

// prep kernel block ranges
#define PREP_RB 216         // repack: 55296 threads
#define PREP_PB 1239        // pad_zero: 316932 threads
#define PREP_TB 279         // transpose: 71424 threads
#define PREP_NB (PREP_RB + PREP_PB + PREP_TB)

typedef _Float16 half8   __attribute__((ext_vector_type(8)));
typedef _Float16 half4v  __attribute__((ext_vector_type(4)));
typedef float    float4v __attribute__((ext_vector_type(4)));

__device__ __forceinline__ void gl_lds16(const _Float16* g, _Float16* l) {
  __builtin_amdgcn_global_load_lds(
      (const __attribute__((address_space(1))) unsigned int*)(g),
      (__attribute__((address_space(3))) unsigned int*)(l), 16, 0, 0);
}

// -------- fused prep: weight repack + border zero + interior transpose --------
// repack: w[co][ci][27] fp32 -> wr2[t][kc][cog][quad][lw][ci8] fp16
__global__ __launch_bounds__(256) void prep_k(const float* __restrict__ w,
                                              const float* __restrict__ x,
                                              _Float16* __restrict__ wr2,
                                              _Float16* __restrict__ xt) {
  const int bid = blockIdx.x;
  if (bid < PREP_RB) {
    int idx = bid * 256 + threadIdx.x;          // 27*2*16*4*16 = 55296
    int lw   = idx & 15;
    int quad = (idx >> 4) & 3;
    int cog  = (idx >> 6) & 15;
    int tkc  = idx >> 10;          // t*2+kc
    int kc   = tkc & 1;
    int t    = tkc >> 1;
    int co   = cog * 16 + lw;
    int cib  = kc * 32 + quad * 8;
    half8 v;
#pragma unroll
    for (int s = 0; s < 8; s++)
      v[s] = (_Float16)w[(size_t)co * 1728 + (size_t)(cib + s) * 27 + t];
    *(half8*)(wr2 + (size_t)idx * 8) = v;
  } else if (bid < PREP_RB + PREP_PB) {
    int p = (bid - PREP_RB) * 256 + threadIdx.x;
    if (p >= PDHW_) return;
    int pd  = p / PHW_;
    int rem = p - pd * PHW_;
    int ph  = rem / PW_;
    int pw  = rem - ph * PW_;
    bool in = (pd >= 1) & (pd <= DD_) & (ph >= 1) & (ph <= HH_) & (pw >= 1) & (pw <= WW_);
    if (in) return;
    half8 z = (half8)(_Float16)0.f;
#pragma unroll
    for (int cig = 0; cig < 8; cig++)
      *(half8*)(xt + ((size_t)cig * PDHW_ + p) * 8) = z;
  } else {
    int idx = (bid - PREP_RB - PREP_PB) * 256 + threadIdx.x;  // 31*96*24 = 71424
    if (idx >= 31 * 96 * 24) return;
    int wq  = idx % 24;
    int rem = idx / 24;
    int h   = rem % 96;
    int d   = rem / 96;
    const float* xp = x + (size_t)d * HW_ + (size_t)h * WW_ + wq * 4;
    size_t p0 = (size_t)(d + 1) * PHW_ + (size_t)(h + 1) * PW_ + (wq * 4 + 1);
#pragma unroll 1
    for (int cig = 0; cig < 8; cig++) {
      float4 vv[8];
#pragma unroll
      for (int s = 0; s < 8; s++)
        vv[s] = *(const float4*)(xp + (size_t)(cig * 8 + s) * DHW_);
#pragma unroll
      for (int k = 0; k < 4; k++) {
        half8 o;
#pragma unroll
        for (int s = 0; s < 8; s++) o[s] = (_Float16)(&vv[s].x)[k];
        *(half8*)(xt + ((size_t)cig * PDHW_ + p0 + k) * 8) = o;
      }
    }
  }
}

__device__ __forceinline__ float tanh_f(float v) {
  float t = __expf(-2.f * fabsf(v));
  return copysignf((1.f - t) * __builtin_amdgcn_rcpf(1.f + t), v);
}
__device__ __forceinline__ float sigm_f(float v) {
  return __builtin_amdgcn_rcpf(1.f + __expf(-v));
}

// -------- conv3d (implicit GEMM, 16x16x32 f16 MFMA) + BN + act -> gates ----
// grid: 2232 blocks (XCD-chunk swizzled). block 512 = 8 waves (2 M x 4 N).
// K loop: 18 groups (kd x kc x kw), kh-row-sharing (6 ds_read feed 48 MFMA).
// Epilogue: XOR-swizzled LDS restage packs 4 gates of each (c,sp) adjacently
// -> [c][sp][g4] global layout, 1KB-contiguous stores per wave.
__global__ __launch_bounds__(512, 4) void conv_mfma_k(
    const _Float16* __restrict__ xt, const _Float16* __restrict__ wr2,
    const float* __restrict__ gamma, const float* __restrict__ beta,
    const float* __restrict__ mean, const float* __restrict__ var,
    _Float16* __restrict__ gates)
{
  __shared__ _Float16 xh[XH_N];

  // XCD-chunked swizzle: 2232 = 8 * 279 exactly (bijective)
  const int bid  = blockIdx.x;
  const int flat = (bid & 7) * 279 + (bid >> 3);
  const int d    = flat / NTILE;
  const int bx   = flat - d * NTILE;
  const int wti  = bx % 6;
  const int hti  = bx / 6;
  const int h0   = hti * 8, w0 = wti * 16;

  const int tid  = threadIdx.x;
  const int lane = tid & 63;
  const int wave = __builtin_amdgcn_readfirstlane(tid >> 6);
  const int wm   = wave >> 2;        // M half (0,1)
  const int wn   = wave & 3;         // co group (64 each)
  const int lw   = lane & 15;        // A: m(spatial w)  B: n(co)
  const int quad = lane >> 4;        // k-group (8 ci)

  // ---- stage halo: 4352 16B tasks, direct global->LDS DMA, all in-bounds ----
#pragma unroll 1
  for (int it = 0; it < 9; ++it) {
    const int wb = it * 512 + wave * 64;       // wave-uniform LDS base task
    if (wb < NTASKP) {
      const int task = wb + lane;
      const int tt   = task < NTASK ? task : (NTASK - 1);  // spare lanes dup
      int col = tt % 18;
      int rc  = tt / 18;
      int cig = rc & 7;
      int dr  = rc >> 3;
      int dd  = dr / 10;
      int row = dr - dd * 10;
      const _Float16* g = xt + (((size_t)cig * PDHW_ + (size_t)(d + dd) * PHW_ +
                                 (size_t)(h0 + row) * PW_ + (w0 + col)) << 3);
      gl_lds16(g, xh + (size_t)wb * 8);
    }
  }

  float4v acc[4][4];
#pragma unroll
  for (int m = 0; m < 4; m++)
#pragma unroll
    for (int j = 0; j < 4; j++) acc[m][j] = (float4v)0.f;

  __syncthreads();   // vmcnt(0) drain of global_load_lds + barrier

  // ---- K loop: 18 groups, kh-row-sharing, fully unrolled ----
  const int abase0 = quad * S_CIG + lw * S_COL + (wm * 4) * S_ROW;
  half8 af[6];
  half8 bf[4];
#pragma unroll
  for (int kd = 0; kd < 3; ++kd) {
#pragma unroll
    for (int kc = 0; kc < 2; ++kc) {
#pragma unroll
      for (int kw = 0; kw < 3; ++kw) {
        const int ab = abase0 + kd * S_DD + kc * (4 * S_CIG) + kw * S_COL;
#pragma unroll
        for (int r = 0; r < 6; ++r)
          af[r] = *(const half8*)(xh + ab + r * S_ROW);
#pragma unroll
        for (int kh = 0; kh < 3; ++kh) {
          const int t = (kd * 3 + kh) * 3 + kw;
          const _Float16* bp =
              wr2 + (((size_t)((t * 2 + kc) * 16 + wn * 4)) << 9) + (lane << 3);
#pragma unroll
          for (int j = 0; j < 4; ++j)
            bf[j] = *(const half8*)(bp + ((size_t)j << 9));
          __builtin_amdgcn_s_setprio(1);
#pragma unroll
          for (int j = 0; j < 4; ++j) {
            acc[0][j] = __builtin_amdgcn_mfma_f32_16x16x32_f16(af[kh    ], bf[j], acc[0][j], 0, 0, 0);
            acc[1][j] = __builtin_amdgcn_mfma_f32_16x16x32_f16(af[kh + 1], bf[j], acc[1][j], 0, 0, 0);
            acc[2][j] = __builtin_amdgcn_mfma_f32_16x16x32_f16(af[kh + 2], bf[j], acc[2][j], 0, 0, 0);
            acc[3][j] = __builtin_amdgcn_mfma_f32_16x16x32_f16(af[kh + 3], bf[j], acc[3][j], 0, 0, 0);
          }
          __builtin_amdgcn_s_setprio(0);
        }
      }
    }
  }

  // ---- epilogue: BN + act -> swizzled LDS restage -> packed [c][sp][g4] ----
  __syncthreads();   // all A-reads done; halo LDS is dead, reuse as 64KB tile

  // LDS tile bytes: c*1024 + ((sp*8 + wn*2) ^ ((c&7)<<4))  (bijective per c)
  const bool istanh = (wn == 0) || (wn == 3);
#pragma unroll
  for (int j = 0; j < 4; j++) {
    const int co = wn * 64 + j * 16 + lw;
    const int c  = j * 16 + lw;
    const float s  = gamma[co] * rsqrtf(var[co] + EPSV);
    const float bb = fmaf(-mean[co], s, beta[co]);
    const int cbase = c << 10;
    const int key   = (c & 7) << 4;
#pragma unroll
    for (int m = 0; m < 4; m++) {
#pragma unroll
      for (int reg = 0; reg < 4; reg++) {
        float v = fmaf(acc[m][j][reg], s, bb);
        _Float16 a = (_Float16)(istanh ? tanh_f(v) : sigm_f(v));
        const int sp = wm * 64 + m * 16 + quad * 4 + reg;
        *(_Float16*)((char*)xh + cbase + (((sp << 3) + (wn << 1)) ^ key)) = a;
      }
    }
  }
  __syncthreads();

  // coalesced read-out: 8 rounds, c = wave*8+r, sp-pair = lane -> 16B each
  _Float16* gb = gates + (size_t)(d * NTILE + bx) * GBLK;
#pragma unroll
  for (int r = 0; r < 8; r++) {
    const int c = wave * 8 + r;
    const half8 rv = *(const half8*)((const char*)xh + (c << 10) +
                                     ((lane ^ (c & 7)) << 4));
    *(half8*)(gb + (size_t)c * 512 + lane * 8) = rv;   // 1KB contiguous/wave
  }
}

// -------- SRU recurrence over d; ONE thread per (c, bx, sp); 8-deep ring ----
// gates: [c][sp][g4] -> per d a single 8B half4 {wx,f,r,x}; loads independent.
// Non-temporal out stores (write-once) keep L2 for the gate stream.
__global__ __launch_bounds__(256) void recurrence_k(const _Float16* __restrict__ gates,
                                                    float* __restrict__ out) {
  const int idx = blockIdx.x * 256 + threadIdx.x;   // 64*72*128 = 589824
  const int sp  = idx & 127;
  const int t2  = idx >> 7;          // c*72 + bx
  const int c   = t2 / NTILE;
  const int bx  = t2 - c * NTILE;
  const int hti = bx / 6, wti = bx - hti * 6;
  const int h   = hti * 8 + (sp >> 4);
  const int w   = wti * 16 + (sp & 15);

  const _Float16* g0 = gates + (size_t)bx * GBLK + (size_t)c * 512 + sp * 4;
  float* op = out + (size_t)c * DHW_ + (size_t)h * WW_ + w;

#define LD(dv) (*(const half4v*)(g0 + (size_t)(dv) * GDSTR))
  half4v p[8];
#pragma unroll
  for (int i = 0; i < 8; i++) p[i] = LD(i);

  float C = 0.f;
#pragma unroll
  for (int d = 0; d < DD_; d++) {       // fully unrolled: p[d&7] is static
    half4v cur = p[d & 7];
    if (d + 8 < DD_) p[d & 7] = LD(d + 8);
    float wx = (float)cur[0], f = (float)cur[1];
    float r  = (float)cur[2], x = (float)cur[3];
    C = (d == 0) ? (1.f - f) : fmaf(f, C - wx, wx);
    __builtin_nontemporal_store(fmaf(r, C - x, x), &op[(size_t)d * HW_]);
  }
#undef LD
}

extern "C" void kernel_launch(void* const* d_in, const int* in_sizes, int n_in,
                              void* d_out, int out_size, void* d_ws, size_t ws_size,
                              hipStream_t stream) {
  const float* x     = (const float*)d_in[0];
  const float* w     = (const float*)d_in[1];
  const float* gamma = (const float*)d_in[2];
  const float* beta  = (const float*)d_in[3];
  const float* mean  = (const float*)d_in[4];
  const float* var   = (const float*)d_in[5];
  float* out = (float*)d_out;

  // ws: [wr2: 884736 B][xt: 8*316932*16 = 40567296 B][gates: 2232*65536 B]
  _Float16* wr2   = (_Float16*)d_ws;
  _Float16* xt    = (_Float16*)((char*)d_ws + 884736);
  _Float16* gates = (_Float16*)((char*)d_ws + 884736 + 40567296);

  prep_k<<<PREP_NB, 256, 0, stream>>>(w, x, wr2, xt);
  conv_mfma_k<<<NBLK, 512, 0, stream>>>(xt, wr2, gamma, beta, mean, var, gates);
  recurrence_k<<<(64 * NTILE * 128) / 256, 256, 0, stream>>>(gates, out);
}

// Round 13
// 396.825 us; speedup vs baseline: 1.9830x; 1.0068x over previous
//
#include <hip/hip_runtime.h>
#include <cstddef>

// Problem dims
#define CI_  64
#define CO_  256
#define DD_  31
#define HH_  96
#define WW_  96
#define HW_  (HH_*WW_)      // 9216
#define DHW_ (DD_*HW_)      // 285696
#define EPSV 1e-5f

// Padded channels-last fp16 input: xt[cig8][pd33][ph98][pw98][ci8]
#define PD_   33
#define PH_   98
#define PW_   98
#define PHW_  9604          // 98*98
#define PDHW_ 316932        // 33*9604

// Conv tile: M=128 (8h x 16w) x N=256, one d per block. 8 waves: 2 (M) x 4 (N).
// LDS halo: [dd3][row10][cig8][col18][ci8] halves — linear in task order.
#define S_COL 8
#define S_CIG 144           // 18*8
#define S_ROW 1152          // 8*144
#define S_DD  11520         // 10*1152
#define NTASK 4320          // 3*10*8*18 real 16B tasks
#define NTASKP 4352         // padded
#define XH_N  (NTASKP*8)    // 34816 halves = 69632 B

#define NTILE 72            // 12 hti * 6 wti per d-plane
#define NBLK  (NTILE*DD_)   // 2232 conv blocks (= 8*279, XCD-exact)

// gates layout: per (d,bx) block of 32768 halves: [c 64][sp 128][gate 4]
#define GBLK 32768
#define GDSTR ((size_t)NTILE * GBLK)

// prep kernel block ranges
#define PREP_RB 216         // repack: 55296 threads
#define PREP_PB 1239        // pad_zero border: 316932 positions
#define PREP_TB 2232        // transpose: 8*31*96*24 = 571392 threads (cig-parallel)
#define PREP_NB (PREP_RB + PREP_PB + PREP_TB)

typedef _Float16 half8   __attribute__((ext_vector_type(8)));
typedef _Float16 half4v  __attribute__((ext_vector_type(4)));
typedef float    float4v __attribute__((ext_vector_type(4)));
typedef float    float2v __attribute__((ext_vector_type(2)));

__device__ __forceinline__ void gl_lds16(const _Float16* g, _Float16* l) {
  __builtin_amdgcn_global_load_lds(
      (const __attribute__((address_space(1))) unsigned int*)(g),
      (__attribute__((address_space(3))) unsigned int*)(l), 16, 0, 0);
}

// -------- fused prep: weight repack + border zero + interior transpose --------
// repack: w[co][ci][27] fp32 -> wr2[t][kc][cog][quad][lw][ci8] fp16
// transpose: cig-parallel (8x TLP vs r11) — one thread per (cig,d,h,wq)
__global__ __launch_bounds__(256) void prep_k(const float* __restrict__ w,
                                              const float* __restrict__ x,
                                              _Float16* __restrict__ wr2,
                                              _Float16* __restrict__ xt) {
  const int bid = blockIdx.x;
  if (bid < PREP_RB) {
    int idx = bid * 256 + threadIdx.x;          // 27*2*16*4*16 = 55296
    int lw   = idx & 15;
    int quad = (idx >> 4) & 3;
    int cog  = (idx >> 6) & 15;
    int tkc  = idx >> 10;          // t*2+kc
    int kc   = tkc & 1;
    int t    = tkc >> 1;
    int co   = cog * 16 + lw;
    int cib  = kc * 32 + quad * 8;
    half8 v;
#pragma unroll
    for (int s = 0; s < 8; s++)
      v[s] = (_Float16)w[(size_t)co * 1728 + (size_t)(cib + s) * 27 + t];
    *(half8*)(wr2 + (size_t)idx * 8) = v;
  } else if (bid < PREP_RB + PREP_PB) {
    int p = (bid - PREP_RB) * 256 + threadIdx.x;
    if (p >= PDHW_) return;
    int pd  = p / PHW_;
    int rem = p - pd * PHW_;
    int ph  = rem / PW_;
    int pw  = rem - ph * PW_;
    bool in = (pd >= 1) & (pd <= DD_) & (ph >= 1) & (ph <= HH_) & (pw >= 1) & (pw <= WW_);
    if (in) return;
    half8 z = (half8)(_Float16)0.f;
#pragma unroll
    for (int cig = 0; cig < 8; cig++)
      *(half8*)(xt + ((size_t)cig * PDHW_ + p) * 8) = z;
  } else {
    int idx = (bid - PREP_RB - PREP_PB) * 256 + threadIdx.x;  // 8*31*96*24
    int wq   = idx % 24;
    int rem  = idx / 24;
    int h    = rem % 96;
    int rem2 = rem / 96;
    int d    = rem2 % 31;
    int cig  = rem2 / 31;
    const float* xp = x + (size_t)(cig * 8) * DHW_ + (size_t)d * HW_ +
                      (size_t)h * WW_ + wq * 4;
    size_t p0 = (size_t)(d + 1) * PHW_ + (size_t)(h + 1) * PW_ + (wq * 4 + 1);
    float4 vv[8];
#pragma unroll
    for (int s = 0; s < 8; s++)
      vv[s] = *(const float4*)(xp + (size_t)s * DHW_);
#pragma unroll
    for (int k = 0; k < 4; k++) {
      half8 o;
#pragma unroll
      for (int s = 0; s < 8; s++) o[s] = (_Float16)(&vv[s].x)[k];
      *(half8*)(xt + ((size_t)cig * PDHW_ + p0 + k) * 8) = o;
    }
  }
}

__device__ __forceinline__ float tanh_f(float v) {
  float t = __expf(-2.f * fabsf(v));
  return copysignf((1.f - t) * __builtin_amdgcn_rcpf(1.f + t), v);
}
__device__ __forceinline__ float sigm_f(float v) {
  return __builtin_amdgcn_rcpf(1.f + __expf(-v));
}

// -------- conv3d (implicit GEMM, 16x16x32 f16 MFMA) + BN + act -> gates ----
// grid: 2232 blocks (XCD-chunk swizzled). block 512 = 8 waves (2 M x 4 N).
// K loop: 18 groups (kd x kc x kw), kh-row-sharing (6 ds_read feed 48 MFMA).
// Epilogue: XOR-swizzled LDS restage packs 4 gates of each (c,sp) adjacently
// -> [c][sp][g4] global layout, 1KB-contiguous stores per wave.
// (held byte-identical to r11 — control)
__global__ __launch_bounds__(512, 4) void conv_mfma_k(
    const _Float16* __restrict__ xt, const _Float16* __restrict__ wr2,
    const float* __restrict__ gamma, const float* __restrict__ beta,
    const float* __restrict__ mean, const float* __restrict__ var,
    _Float16* __restrict__ gates)
{
  __shared__ _Float16 xh[XH_N];

  // XCD-chunked swizzle: 2232 = 8 * 279 exactly (bijective)
  const int bid  = blockIdx.x;
  const int flat = (bid & 7) * 279 + (bid >> 3);
  const int d    = flat / NTILE;
  const int bx   = flat - d * NTILE;
  const int wti  = bx % 6;
  const int hti  = bx / 6;
  const int h0   = hti * 8, w0 = wti * 16;

  const int tid  = threadIdx.x;
  const int lane = tid & 63;
  const int wave = __builtin_amdgcn_readfirstlane(tid >> 6);
  const int wm   = wave >> 2;        // M half (0,1)
  const int wn   = wave & 3;         // co group (64 each)
  const int lw   = lane & 15;        // A: m(spatial w)  B: n(co)
  const int quad = lane >> 4;        // k-group (8 ci)

  // ---- stage halo: 4352 16B tasks, direct global->LDS DMA, all in-bounds ----
#pragma unroll 1
  for (int it = 0; it < 9; ++it) {
    const int wb = it * 512 + wave * 64;       // wave-uniform LDS base task
    if (wb < NTASKP) {
      const int task = wb + lane;
      const int tt   = task < NTASK ? task : (NTASK - 1);  // spare lanes dup
      int col = tt % 18;
      int rc  = tt / 18;
      int cig = rc & 7;
      int dr  = rc >> 3;
      int dd  = dr / 10;
      int row = dr - dd * 10;
      const _Float16* g = xt + (((size_t)cig * PDHW_ + (size_t)(d + dd) * PHW_ +
                                 (size_t)(h0 + row) * PW_ + (w0 + col)) << 3);
      gl_lds16(g, xh + (size_t)wb * 8);
    }
  }

  float4v acc[4][4];
#pragma unroll
  for (int m = 0; m < 4; m++)
#pragma unroll
    for (int j = 0; j < 4; j++) acc[m][j] = (float4v)0.f;

  __syncthreads();   // vmcnt(0) drain of global_load_lds + barrier

  // ---- K loop: 18 groups, kh-row-sharing, fully unrolled ----
  const int abase0 = quad * S_CIG + lw * S_COL + (wm * 4) * S_ROW;
  half8 af[6];
  half8 bf[4];
#pragma unroll
  for (int kd = 0; kd < 3; ++kd) {
#pragma unroll
    for (int kc = 0; kc < 2; ++kc) {
#pragma unroll
      for (int kw = 0; kw < 3; ++kw) {
        const int ab = abase0 + kd * S_DD + kc * (4 * S_CIG) + kw * S_COL;
#pragma unroll
        for (int r = 0; r < 6; ++r)
          af[r] = *(const half8*)(xh + ab + r * S_ROW);
#pragma unroll
        for (int kh = 0; kh < 3; ++kh) {
          const int t = (kd * 3 + kh) * 3 + kw;
          const _Float16* bp =
              wr2 + (((size_t)((t * 2 + kc) * 16 + wn * 4)) << 9) + (lane << 3);
#pragma unroll
          for (int j = 0; j < 4; ++j)
            bf[j] = *(const half8*)(bp + ((size_t)j << 9));
          __builtin_amdgcn_s_setprio(1);
#pragma unroll
          for (int j = 0; j < 4; ++j) {
            acc[0][j] = __builtin_amdgcn_mfma_f32_16x16x32_f16(af[kh    ], bf[j], acc[0][j], 0, 0, 0);
            acc[1][j] = __builtin_amdgcn_mfma_f32_16x16x32_f16(af[kh + 1], bf[j], acc[1][j], 0, 0, 0);
            acc[2][j] = __builtin_amdgcn_mfma_f32_16x16x32_f16(af[kh + 2], bf[j], acc[2][j], 0, 0, 0);
            acc[3][j] = __builtin_amdgcn_mfma_f32_16x16x32_f16(af[kh + 3], bf[j], acc[3][j], 0, 0, 0);
          }
          __builtin_amdgcn_s_setprio(0);
        }
      }
    }
  }

  // ---- epilogue: BN + act -> swizzled LDS restage -> packed [c][sp][g4] ----
  __syncthreads();   // all A-reads done; halo LDS is dead, reuse as 64KB tile

  // LDS tile bytes: c*1024 + ((sp*8 + wn*2) ^ ((c&7)<<4))  (bijective per c)
  const bool istanh = (wn == 0) || (wn == 3);
#pragma unroll
  for (int j = 0; j < 4; j++) {
    const int co = wn * 64 + j * 16 + lw;
    const int c  = j * 16 + lw;
    const float s  = gamma[co] * rsqrtf(var[co] + EPSV);
    const float bb = fmaf(-mean[co], s, beta[co]);
    const int cbase = c << 10;
    const int key   = (c & 7) << 4;
#pragma unroll
    for (int m = 0; m < 4; m++) {
#pragma unroll
      for (int reg = 0; reg < 4; reg++) {
        float v = fmaf(acc[m][j][reg], s, bb);
        _Float16 a = (_Float16)(istanh ? tanh_f(v) : sigm_f(v));
        const int sp = wm * 64 + m * 16 + quad * 4 + reg;
        *(_Float16*)((char*)xh + cbase + (((sp << 3) + (wn << 1)) ^ key)) = a;
      }
    }
  }
  __syncthreads();

  // coalesced read-out: 8 rounds, c = wave*8+r, sp-pair = lane -> 16B each
  _Float16* gb = gates + (size_t)(d * NTILE + bx) * GBLK;
#pragma unroll
  for (int r = 0; r < 8; r++) {
    const int c = wave * 8 + r;
    const half8 rv = *(const half8*)((const char*)xh + (c << 10) +
                                     ((lane ^ (c & 7)) << 4));
    *(half8*)(gb + (size_t)c * 512 + lane * 8) = rv;   // 1KB contiguous/wave
  }
}

// -------- SRU recurrence over d; thread per (c, bx, 2 sp); 8-deep NT ring ----
// gates: [c][sp][g4] -> per d one 16B NT load = {wx,f,r,x} x 2 sp.
// NT loads+stores: both streams touched exactly once.
__global__ __launch_bounds__(256) void recurrence_k(const _Float16* __restrict__ gates,
                                                    float* __restrict__ out) {
  const int idx = blockIdx.x * 256 + threadIdx.x;   // 64*72*64 = 294912
  const int q   = idx & 63;          // sp pair
  const int t2  = idx >> 6;          // c*72 + bx
  const int c   = t2 / NTILE;
  const int bx  = t2 - c * NTILE;
  const int hti = bx / 6, wti = bx - hti * 6;
  const int sp  = q * 2;
  const int h   = hti * 8 + (sp >> 4);
  const int w   = wti * 16 + (sp & 15);   // sp even -> sp, sp+1 same h row

  const _Float16* g0 = gates + (size_t)bx * GBLK + (size_t)c * 512 + sp * 4;
  float* op = out + (size_t)c * DHW_ + (size_t)h * WW_ + w;

#define LD(dv) (__builtin_nontemporal_load((const half8*)(g0 + (size_t)(dv) * GDSTR)))
  half8 p[8];
#pragma unroll
  for (int i = 0; i < 8; i++) p[i] = LD(i);

  float C0 = 0.f, C1 = 0.f;
#pragma unroll
  for (int d = 0; d < DD_; d++) {       // fully unrolled: p[d&7] is static
    half8 cur = p[d & 7];
    if (d + 8 < DD_) p[d & 7] = LD(d + 8);
    float wx0 = (float)cur[0], f0 = (float)cur[1];
    float r0  = (float)cur[2], x0 = (float)cur[3];
    float wx1 = (float)cur[4], f1 = (float)cur[5];
    float r1  = (float)cur[6], x1 = (float)cur[7];
    C0 = (d == 0) ? (1.f - f0) : fmaf(f0, C0 - wx0, wx0);
    C1 = (d == 0) ? (1.f - f1) : fmaf(f1, C1 - wx1, wx1);
    float2v st = {fmaf(r0, C0 - x0, x0), fmaf(r1, C1 - x1, x1)};
    __builtin_nontemporal_store(st, (float2v*)(op + (size_t)d * HW_));
  }
#undef LD
}

extern "C" void kernel_launch(void* const* d_in, const int* in_sizes, int n_in,
                              void* d_out, int out_size, void* d_ws, size_t ws_size,
                              hipStream_t stream) {
  const float* x     = (const float*)d_in[0];
  const float* w     = (const float*)d_in[1];
  const float* gamma = (const float*)d_in[2];
  const float* beta  = (const float*)d_in[3];
  const float* mean  = (const float*)d_in[4];
  const float* var   = (const float*)d_in[5];
  float* out = (float*)d_out;

  // ws: [wr2: 884736 B][xt: 8*316932*16 = 40567296 B][gates: 2232*65536 B]
  _Float16* wr2   = (_Float16*)d_ws;
  _Float16* xt    = (_Float16*)((char*)d_ws + 884736);
  _Float16* gates = (_Float16*)((char*)d_ws + 884736 + 40567296);

  prep_k<<<PREP_NB, 256, 0, stream>>>(w, x, wr2, xt);
  conv_mfma_k<<<NBLK, 512, 0, stream>>>(xt, wr2, gamma, beta, mean, var, gates);
  recurrence_k<<<(64 * NTILE * 64) / 256, 256, 0, stream>>>(gates, out);
}

// Round 14
// 385.843 us; speedup vs baseline: 2.0395x; 1.0285x over previous
//
#include <hip/hip_runtime.h>
#include <cstddef>

// Problem dims
#define CI_  64
#define CO_  256
#define DD_  31
#define HH_  96
#define WW_  96
#define HW_  (HH_*WW_)      // 9216
#define DHW_ (DD_*HW_)      // 285696
#define EPSV 1e-5f

// Padded channels-last fp16 input: xt[cig8][pd33][ph98][pw98][ci8]
#define PD_   33
#define PH_   98
#define PW_   98
#define PHW_  9604          // 98*98
#define PDHW_ 316932        // 33*9604

// Conv tile: M=128 (8h x 16w) x N=256, one d per block. 8 waves: 2 (M) x 4 (N).
// LDS halo: [dd3][row10][cig8][col18][ci8] halves — linear in task order.
#define S_COL 8
#define S_CIG 144           // 18*8
#define S_ROW 1152          // 8*144
#define S_DD  11520         // 10*1152
#define NTASK 4320          // 3*10*8*18 real 16B tasks
#define NTASKP 4352         // padded
#define XH_N  (NTASKP*8)    // 34816 halves = 69632 B

#define NTILE 72            // 12 hti * 6 wti per d-plane
#define NBLK  (NTILE*DD_)   // 2232 conv blocks (= 8*279, XCD-exact)

// gates layout: per (d,bx) block of 32768 halves: [c 64][sp 128][gate 4]
#define GBLK 32768
#define GDSTR ((size_t)NTILE * GBLK)

// prep kernel block ranges
#define PREP_RB 216         // repack: 55296 threads
#define PREP_PB 1239        // pad_zero border: 316932 positions
#define PREP_TB 2232        // transpose: 8*31*96*24 = 571392 threads (cig-parallel)
#define PREP_NB (PREP_RB + PREP_PB + PREP_TB)

typedef _Float16 half8   __attribute__((ext_vector_type(8)));
typedef _Float16 half4v  __attribute__((ext_vector_type(4)));
typedef float    float4v __attribute__((ext_vector_type(4)));
typedef float    float2v __attribute__((ext_vector_type(2)));

__device__ __forceinline__ void gl_lds16(const _Float16* g, _Float16* l) {
  __builtin_amdgcn_global_load_lds(
      (const __attribute__((address_space(1))) unsigned int*)(g),
      (__attribute__((address_space(3))) unsigned int*)(l), 16, 0, 0);
}

// -------- fused prep: weight repack + border zero + interior transpose --------
// repack: w[co][ci][27] fp32 -> wr2[t][kc][cog][quad][lw][ci8] fp16
// transpose: cig-parallel — one thread per (cig,d,h,wq)
__global__ __launch_bounds__(256) void prep_k(const float* __restrict__ w,
                                              const float* __restrict__ x,
                                              _Float16* __restrict__ wr2,
                                              _Float16* __restrict__ xt) {
  const int bid = blockIdx.x;
  if (bid < PREP_RB) {
    int idx = bid * 256 + threadIdx.x;          // 27*2*16*4*16 = 55296
    int lw   = idx & 15;
    int quad = (idx >> 4) & 3;
    int cog  = (idx >> 6) & 15;
    int tkc  = idx >> 10;          // t*2+kc
    int kc   = tkc & 1;
    int t    = tkc >> 1;
    int co   = cog * 16 + lw;
    int cib  = kc * 32 + quad * 8;
    half8 v;
#pragma unroll
    for (int s = 0; s < 8; s++)
      v[s] = (_Float16)w[(size_t)co * 1728 + (size_t)(cib + s) * 27 + t];
    *(half8*)(wr2 + (size_t)idx * 8) = v;
  } else if (bid < PREP_RB + PREP_PB) {
    int p = (bid - PREP_RB) * 256 + threadIdx.x;
    if (p >= PDHW_) return;
    int pd  = p / PHW_;
    int rem = p - pd * PHW_;
    int ph  = rem / PW_;
    int pw  = rem - ph * PW_;
    bool in = (pd >= 1) & (pd <= DD_) & (ph >= 1) & (ph <= HH_) & (pw >= 1) & (pw <= WW_);
    if (in) return;
    half8 z = (half8)(_Float16)0.f;
#pragma unroll
    for (int cig = 0; cig < 8; cig++)
      *(half8*)(xt + ((size_t)cig * PDHW_ + p) * 8) = z;
  } else {
    int idx = (bid - PREP_RB - PREP_PB) * 256 + threadIdx.x;  // 8*31*96*24
    int wq   = idx % 24;
    int rem  = idx / 24;
    int h    = rem % 96;
    int rem2 = rem / 96;
    int d    = rem2 % 31;
    int cig  = rem2 / 31;
    const float* xp = x + (size_t)(cig * 8) * DHW_ + (size_t)d * HW_ +
                      (size_t)h * WW_ + wq * 4;
    size_t p0 = (size_t)(d + 1) * PHW_ + (size_t)(h + 1) * PW_ + (wq * 4 + 1);
    float4 vv[8];
#pragma unroll
    for (int s = 0; s < 8; s++)
      vv[s] = *(const float4*)(xp + (size_t)s * DHW_);
#pragma unroll
    for (int k = 0; k < 4; k++) {
      half8 o;
#pragma unroll
      for (int s = 0; s < 8; s++) o[s] = (_Float16)(&vv[s].x)[k];
      *(half8*)(xt + ((size_t)cig * PDHW_ + p0 + k) * 8) = o;
    }
  }
}

__device__ __forceinline__ float tanh_f(float v) {
  float t = __expf(-2.f * fabsf(v));
  return copysignf((1.f - t) * __builtin_amdgcn_rcpf(1.f + t), v);
}
__device__ __forceinline__ float sigm_f(float v) {
  return __builtin_amdgcn_rcpf(1.f + __expf(-v));
}

// -------- conv3d (implicit GEMM, 16x16x32 f16 MFMA) + BN + act -> gates ----
// grid: 2232 blocks (XCD-chunk swizzled). block 512 = 8 waves (2 M x 4 N).
// K loop: 18 groups (kd x kc x kw), kh-row-sharing (6 ds_read feed 48 MFMA).
// Epilogue: XOR-swizzled LDS restage packs 4 gates of each (c,sp) adjacently
// -> [c][sp][g4] global layout, 1KB-contiguous stores per wave.
// (held byte-identical — control)
__global__ __launch_bounds__(512, 4) void conv_mfma_k(
    const _Float16* __restrict__ xt, const _Float16* __restrict__ wr2,
    const float* __restrict__ gamma, const float* __restrict__ beta,
    const float* __restrict__ mean, const float* __restrict__ var,
    _Float16* __restrict__ gates)
{
  __shared__ _Float16 xh[XH_N];

  // XCD-chunked swizzle: 2232 = 8 * 279 exactly (bijective)
  const int bid  = blockIdx.x;
  const int flat = (bid & 7) * 279 + (bid >> 3);
  const int d    = flat / NTILE;
  const int bx   = flat - d * NTILE;
  const int wti  = bx % 6;
  const int hti  = bx / 6;
  const int h0   = hti * 8, w0 = wti * 16;

  const int tid  = threadIdx.x;
  const int lane = tid & 63;
  const int wave = __builtin_amdgcn_readfirstlane(tid >> 6);
  const int wm   = wave >> 2;        // M half (0,1)
  const int wn   = wave & 3;         // co group (64 each)
  const int lw   = lane & 15;        // A: m(spatial w)  B: n(co)
  const int quad = lane >> 4;        // k-group (8 ci)

  // ---- stage halo: 4352 16B tasks, direct global->LDS DMA, all in-bounds ----
#pragma unroll 1
  for (int it = 0; it < 9; ++it) {
    const int wb = it * 512 + wave * 64;       // wave-uniform LDS base task
    if (wb < NTASKP) {
      const int task = wb + lane;
      const int tt   = task < NTASK ? task : (NTASK - 1);  // spare lanes dup
      int col = tt % 18;
      int rc  = tt / 18;
      int cig = rc & 7;
      int dr  = rc >> 3;
      int dd  = dr / 10;
      int row = dr - dd * 10;
      const _Float16* g = xt + (((size_t)cig * PDHW_ + (size_t)(d + dd) * PHW_ +
                                 (size_t)(h0 + row) * PW_ + (w0 + col)) << 3);
      gl_lds16(g, xh + (size_t)wb * 8);
    }
  }

  float4v acc[4][4];
#pragma unroll
  for (int m = 0; m < 4; m++)
#pragma unroll
    for (int j = 0; j < 4; j++) acc[m][j] = (float4v)0.f;

  __syncthreads();   // vmcnt(0) drain of global_load_lds + barrier

  // ---- K loop: 18 groups, kh-row-sharing, fully unrolled ----
  const int abase0 = quad * S_CIG + lw * S_COL + (wm * 4) * S_ROW;
  half8 af[6];
  half8 bf[4];
#pragma unroll
  for (int kd = 0; kd < 3; ++kd) {
#pragma unroll
    for (int kc = 0; kc < 2; ++kc) {
#pragma unroll
      for (int kw = 0; kw < 3; ++kw) {
        const int ab = abase0 + kd * S_DD + kc * (4 * S_CIG) + kw * S_COL;
#pragma unroll
        for (int r = 0; r < 6; ++r)
          af[r] = *(const half8*)(xh + ab + r * S_ROW);
#pragma unroll
        for (int kh = 0; kh < 3; ++kh) {
          const int t = (kd * 3 + kh) * 3 + kw;
          const _Float16* bp =
              wr2 + (((size_t)((t * 2 + kc) * 16 + wn * 4)) << 9) + (lane << 3);
#pragma unroll
          for (int j = 0; j < 4; ++j)
            bf[j] = *(const half8*)(bp + ((size_t)j << 9));
          __builtin_amdgcn_s_setprio(1);
#pragma unroll
          for (int j = 0; j < 4; ++j) {
            acc[0][j] = __builtin_amdgcn_mfma_f32_16x16x32_f16(af[kh    ], bf[j], acc[0][j], 0, 0, 0);
            acc[1][j] = __builtin_amdgcn_mfma_f32_16x16x32_f16(af[kh + 1], bf[j], acc[1][j], 0, 0, 0);
            acc[2][j] = __builtin_amdgcn_mfma_f32_16x16x32_f16(af[kh + 2], bf[j], acc[2][j], 0, 0, 0);
            acc[3][j] = __builtin_amdgcn_mfma_f32_16x16x32_f16(af[kh + 3], bf[j], acc[3][j], 0, 0, 0);
          }
          __builtin_amdgcn_s_setprio(0);
        }
      }
    }
  }

  // ---- epilogue: BN + act -> swizzled LDS restage -> packed [c][sp][g4] ----
  __syncthreads();   // all A-reads done; halo LDS is dead, reuse as 64KB tile

  // LDS tile bytes: c*1024 + ((sp*8 + wn*2) ^ ((c&7)<<4))  (bijective per c)
  const bool istanh = (wn == 0) || (wn == 3);
#pragma unroll
  for (int j = 0; j < 4; j++) {
    const int co = wn * 64 + j * 16 + lw;
    const int c  = j * 16 + lw;
    const float s  = gamma[co] * rsqrtf(var[co] + EPSV);
    const float bb = fmaf(-mean[co], s, beta[co]);
    const int cbase = c << 10;
    const int key   = (c & 7) << 4;
#pragma unroll
    for (int m = 0; m < 4; m++) {
#pragma unroll
      for (int reg = 0; reg < 4; reg++) {
        float v = fmaf(acc[m][j][reg], s, bb);
        _Float16 a = (_Float16)(istanh ? tanh_f(v) : sigm_f(v));
        const int sp = wm * 64 + m * 16 + quad * 4 + reg;
        *(_Float16*)((char*)xh + cbase + (((sp << 3) + (wn << 1)) ^ key)) = a;
      }
    }
  }
  __syncthreads();

  // coalesced read-out: 8 rounds, c = wave*8+r, sp-pair = lane -> 16B each
  _Float16* gb = gates + (size_t)(d * NTILE + bx) * GBLK;
#pragma unroll
  for (int r = 0; r < 8; r++) {
    const int c = wave * 8 + r;
    const half8 rv = *(const half8*)((const char*)xh + (c << 10) +
                                     ((lane ^ (c & 7)) << 4));
    *(half8*)(gb + (size_t)c * 512 + lane * 8) = rv;   // 1KB contiguous/wave
  }
}

// -------- SRU recurrence over d; thread per (c, bx, 2 sp); 8-deep ring ----
// gates: [c][sp][g4] -> per d one 16B load = {wx,f,r,x} x 2 sp.
// Gate loads are REGULAR (L3-resident after conv — NT hint was bypassing MALL);
// out stores stay NT (write-once, never re-read).
__global__ __launch_bounds__(256) void recurrence_k(const _Float16* __restrict__ gates,
                                                    float* __restrict__ out) {
  const int idx = blockIdx.x * 256 + threadIdx.x;   // 64*72*64 = 294912
  const int q   = idx & 63;          // sp pair
  const int t2  = idx >> 6;          // c*72 + bx
  const int c   = t2 / NTILE;
  const int bx  = t2 - c * NTILE;
  const int hti = bx / 6, wti = bx - hti * 6;
  const int sp  = q * 2;
  const int h   = hti * 8 + (sp >> 4);
  const int w   = wti * 16 + (sp & 15);   // sp even -> sp, sp+1 same h row

  const _Float16* g0 = gates + (size_t)bx * GBLK + (size_t)c * 512 + sp * 4;
  float* op = out + (size_t)c * DHW_ + (size_t)h * WW_ + w;

#define LD(dv) (*(const half8*)(g0 + (size_t)(dv) * GDSTR))
  half8 p[8];
#pragma unroll
  for (int i = 0; i < 8; i++) p[i] = LD(i);

  float C0 = 0.f, C1 = 0.f;
#pragma unroll
  for (int d = 0; d < DD_; d++) {       // fully unrolled: p[d&7] is static
    half8 cur = p[d & 7];
    if (d + 8 < DD_) p[d & 7] = LD(d + 8);
    float wx0 = (float)cur[0], f0 = (float)cur[1];
    float r0  = (float)cur[2], x0 = (float)cur[3];
    float wx1 = (float)cur[4], f1 = (float)cur[5];
    float r1  = (float)cur[6], x1 = (float)cur[7];
    C0 = (d == 0) ? (1.f - f0) : fmaf(f0, C0 - wx0, wx0);
    C1 = (d == 0) ? (1.f - f1) : fmaf(f1, C1 - wx1, wx1);
    float2v st = {fmaf(r0, C0 - x0, x0), fmaf(r1, C1 - x1, x1)};
    __builtin_nontemporal_store(st, (float2v*)(op + (size_t)d * HW_));
  }
#undef LD
}

extern "C" void kernel_launch(void* const* d_in, const int* in_sizes, int n_in,
                              void* d_out, int out_size, void* d_ws, size_t ws_size,
                              hipStream_t stream) {
  const float* x     = (const float*)d_in[0];
  const float* w     = (const float*)d_in[1];
  const float* gamma = (const float*)d_in[2];
  const float* beta  = (const float*)d_in[3];
  const float* mean  = (const float*)d_in[4];
  const float* var   = (const float*)d_in[5];
  float* out = (float*)d_out;

  // ws: [wr2: 884736 B][xt: 8*316932*16 = 40567296 B][gates: 2232*65536 B]
  _Float16* wr2   = (_Float16*)d_ws;
  _Float16* xt    = (_Float16*)((char*)d_ws + 884736);
  _Float16* gates = (_Float16*)((char*)d_ws + 884736 + 40567296);

  prep_k<<<PREP_NB, 256, 0, stream>>>(w, x, wr2, xt);
  conv_mfma_k<<<NBLK, 512, 0, stream>>>(xt, wr2, gamma, beta, mean, var, gates);
  recurrence_k<<<(64 * NTILE * 64) / 256, 256, 0, stream>>>(gates, out);
}